// Round 1
// baseline (227.860 us; speedup 1.0000x reference)
//
#include <hip/hip_runtime.h>

// int4-dequant GEMM: y[m,n] = sum_k x[m,k] * scale[n, k/128] * (q[n,k] - 8)
// x: (512,4096) f32 | weight_packed: (11008,2048) int32 (2 nibbles in low byte) |
// scales: (11008,32) f32 | out: (512,11008) f32
//
// R8: kill split-K. Retile to BM=128 x BN=64 x BK=64, 4 waves of 64x32
// (acc = 32 regs vs R7's 128) -> KS=1 grid of 688 blocks, ALL co-resident at
// 3-4 blocks/CU (R7: 2 blocks/CU, 14% occupancy, latency-bound at 18% MFMA).
// No partials (saves 88 MB write), no reduce_k kernel (saves ~90+88+22 MB pass).
// Freed register budget funds T14 issue-early/write-late prefetch: tile k+1
// global loads issue after barrier-1, land under tile k's MFMA (R6's version
// spilled because 128 AGPR acc + prefetch > 256-reg budget; 32-reg acc fits).
// Preserved verified pieces: dequant sequence, PAD=8 zero-conflict LDS layout
// (measured SQ_LDS_BANK_CONFLICT=0), 32x32x16 C/D store mapping
// (col=lane&31, row=(r&3)+8*(r>>2)+4*(lane>>5)).
// XCD-grouped bijective block swizzle (688 = 8*86): the two m-pairs sharing an
// n-panel (512 KB weights) land on the same XCD for L2 reuse.

typedef __attribute__((ext_vector_type(8)))  short short8;   // 32x32x16 A/B frag
typedef __attribute__((ext_vector_type(16))) float f32x16;   // 32x32x16 C/D frag
typedef __attribute__((ext_vector_type(4)))  float f32x4;
typedef __attribute__((ext_vector_type(4)))  int   i32x4;
typedef __attribute__((ext_vector_type(2)))  int   i32x2;

#define M_DIM 512
#define N_DIM 11008
#define K_DIM 4096
#define BM 128
#define BN 64
#define BK 64
#define PAD 8            // row stride 144B: measured 0 conflicts (R5)
#define THREADS 256
#define NTILE_M (M_DIM / BM)        // 4
#define NTILE_N (N_DIM / BN)        // 172
#define NTILES  (NTILE_M * NTILE_N) // 688 = 8 XCDs * 86
#define KITERS  (K_DIM / BK)        // 64

#if defined(__has_builtin)
#  if __has_builtin(__builtin_amdgcn_cvt_pk_bf16_f32)
#    define HAVE_PK_BF16 1
#  endif
#endif
#ifndef HAVE_PK_BF16
#  define HAVE_PK_BF16 0
#endif

__device__ __forceinline__ unsigned int fbits(float f) {
    union { float f; unsigned int u; } c; c.f = f; return c.u;
}
__device__ __forceinline__ int pack2bf(float lo, float hi) {  // [hi|lo] bf16, RNE
#if HAVE_PK_BF16
    typedef __attribute__((ext_vector_type(2))) __bf16 bf16x2;
    bf16x2 p = __builtin_amdgcn_cvt_pk_bf16_f32(lo, hi);
    int r; __builtin_memcpy(&r, &p, 4);
    return r;
#else
    unsigned int ul = fbits(lo), uh = fbits(hi);
    unsigned int l = (ul + 0x7FFFu + ((ul >> 16) & 1u)) >> 16;
    unsigned int h = (uh + 0x7FFFu + ((uh >> 16) & 1u)) & 0xFFFF0000u;
    return (int)(h | l);
#endif
}

// ---- x f32 -> bf16 workspace ----
__global__ __launch_bounds__(THREADS)
void cvt_x(const float* __restrict__ x, unsigned short* __restrict__ xw)
{
    int idx = (blockIdx.x * THREADS + threadIdx.x) * 4;
    f32x4 v = *(const f32x4*)(x + idx);
    i32x2 p;
    p[0] = pack2bf(v[0], v[1]);
    p[1] = pack2bf(v[2], v[3]);
    *(i32x2*)(xw + idx) = p;
}

// ---- main GEMM: 128x64 tile, 4 waves of 64x32, 32x32x16 MFMA, KS=1 ----
template<bool PRECVT>
__global__ __launch_bounds__(THREADS, 3)
void dq_gemm(const unsigned short* __restrict__ xw,
             const float* __restrict__ xf,
             const int* __restrict__ wp,
             const float* __restrict__ scales,
             float* __restrict__ out)
{
    __shared__ __align__(16) unsigned short sA[BM][BK + PAD];  // 18.4 KB
    __shared__ __align__(16) unsigned short sB[BN][BK + PAD];  //  9.2 KB

    const int t  = threadIdx.x;
    const int bx = blockIdx.x;

    // Bijective XCD-grouped mapping: bx -> (nb, m_idx).
    // xcd = bx&7 (dispatch round-robins %8); w = bx>>3 in [0,86);
    // m_lo = w&1; p = w>>1 in [0,43); g = p*8+xcd in [0,344);
    // nb = g>>1; m = (g&1)*2 + m_lo. For fixed (xcd,p) both m_lo values share
    // (nb, m-pair) -> the 512 KB weight panel is reused within one XCD's L2.
    const int xcd = bx & 7;
    const int w   = bx >> 3;
    const int g_  = (w >> 1) * 8 + xcd;
    const int nb  = g_ >> 1;
    const int m_idx = ((g_ & 1) << 1) | (w & 1);

    const int m0 = m_idx * BM;
    const int n0 = nb * BN;

    const int wave = t >> 6;
    const int lane = t & 63;
    const int wm = (wave & 1) * 64;    // 2 m-waves
    const int wn = (wave >> 1) * 32;   // 2 n-waves
    const int lr = lane & 31;          // frag row
    const int lk = (lane >> 5) * 8;    // frag k

    // staging decomposition (c = i*256 + t):
    const int tr3 = t >> 3;            // row base within 32-row stripe
    const int tc8 = (t & 7) * 8;       // A col (shorts), 16B chunk
    const int tc4 = (t & 7) * 4;       // B col (ints),   16B chunk

    // T14 prefetch registers (fits: 32 acc + 26 stage + addr ~ 110 total)
    i32x4 pa[4];           // PRECVT path: 4 x 16B of bf16 A
    f32x4 paf[8];          // fallback path: 8 x 16B of f32 A
    i32x4 pb[2];
    float sc[2];

    auto LOAD = [&](int kk) {
        const int kb = kk * BK;
        if constexpr (PRECVT) {
            #pragma unroll
            for (int i = 0; i < 4; ++i)
                pa[i] = *(const i32x4*)(xw + (size_t)(m0 + i * 32 + tr3) * K_DIM + kb + tc8);
        } else {
            #pragma unroll
            for (int i = 0; i < 8; ++i) {
                int row = i * 16 + (t >> 4), col = (t & 15) * 4;
                paf[i] = *(const f32x4*)(xf + (size_t)(m0 + row) * K_DIM + kb + col);
            }
        }
        const int gq = kb >> 7;
        #pragma unroll
        for (int i = 0; i < 2; ++i) {
            pb[i] = *(const i32x4*)(wp + (size_t)(n0 + i * 32 + tr3) * (K_DIM / 2) + (kb >> 1) + tc4);
            sc[i] = scales[(size_t)(n0 + i * 32 + tr3) * (K_DIM / 128) + gq];
        }
    };

    auto WRITE = [&]() {
        if constexpr (PRECVT) {
            #pragma unroll
            for (int i = 0; i < 4; ++i)
                *(i32x4*)&sA[i * 32 + tr3][tc8] = pa[i];
        } else {
            #pragma unroll
            for (int i = 0; i < 8; ++i) {
                int row = i * 16 + (t >> 4), col = (t & 15) * 4;
                i32x2 p;
                p[0] = pack2bf(paf[i][0], paf[i][1]);
                p[1] = pack2bf(paf[i][2], paf[i][3]);
                *(i32x2*)&sA[row][col] = p;
            }
        }
        #pragma unroll
        for (int i = 0; i < 2; ++i) {
            float s = sc[i], ns8 = s * -8.0f;
            i32x4 res;
            #pragma unroll
            for (int e = 0; e < 4; ++e) {
                int b = pb[i][e];
                res[e] = pack2bf((float)(b & 15) * s + ns8,
                                 (float)((b >> 4) & 15) * s + ns8);
            }
            *(i32x4*)&sB[i * 32 + tr3][tc4 * 2] = res;
        }
    };

    f32x16 acc[2] = {};

    auto MFMA_PHASE = [&]() {
        #pragma unroll
        for (int ks = 0; ks < BK; ks += 16) {
            short8 a[2], b;
            #pragma unroll
            for (int i = 0; i < 2; ++i)
                a[i] = *(const short8*)&sA[wm + i * 32 + lr][ks + lk];
            b = *(const short8*)&sB[wn + lr][ks + lk];
            #pragma unroll
            for (int i = 0; i < 2; ++i)
                acc[i] = __builtin_amdgcn_mfma_f32_32x32x16_bf16(a[i], b, acc[i], 0, 0, 0);
        }
    };

    LOAD(0);
    for (int kk = 0; kk < KITERS - 1; ++kk) {
        WRITE();                 // regs for tile kk -> LDS (A copy + B dequant)
        __syncthreads();         // tiles ready
        LOAD(kk + 1);            // issue-early: lands under MFMA phase
        MFMA_PHASE();
        __syncthreads();         // all waves done reading before next WRITE
    }
    WRITE();
    __syncthreads();
    MFMA_PHASE();

    // direct store: C/D col=lane&31, row=(r&3)+8*(r>>2)+4*(lane>>5)
    const int rbase = (lane >> 5) * 4;
    #pragma unroll
    for (int i = 0; i < 2; ++i) {
        int mg0 = m0 + wm + i * 32 + rbase;
        int ng  = n0 + wn + lr;
        #pragma unroll
        for (int r = 0; r < 16; ++r)
            out[(size_t)(mg0 + (r & 3) + 8 * (r >> 2)) * N_DIM + ng] = acc[i][r];
    }
}

extern "C" void kernel_launch(void* const* d_in, const int* in_sizes, int n_in,
                              void* d_out, int out_size, void* d_ws, size_t ws_size,
                              hipStream_t stream) {
    (void)in_sizes; (void)n_in; (void)out_size;
    const float* x      = (const float*)d_in[0];
    const int*   wpck   = (const int*)d_in[1];
    const float* scales = (const float*)d_in[2];
    float*       out    = (float*)d_out;

    const size_t XW_BYTES = (size_t)M_DIM * K_DIM * 2;   // 4 MB

    if (ws_size >= XW_BYTES) {
        unsigned short* xw = (unsigned short*)d_ws;
        cvt_x<<<(M_DIM * K_DIM) / (THREADS * 4), THREADS, 0, stream>>>(x, xw);
        dq_gemm<true><<<NTILES, THREADS, 0, stream>>>(xw, x, wpck, scales, out);
    } else {
        dq_gemm<false><<<NTILES, THREADS, 0, stream>>>(nullptr, x, wpck, scales, out);
    }
}